// Round 7
// baseline (99.017 us; speedup 1.0000x reference)
//
#include <hip/hip_runtime.h>
#include <cstdint>
#include <cstddef>

#define DEV __device__ __forceinline__

typedef __attribute__((ext_vector_type(8))) short bf16x8;
typedef __attribute__((ext_vector_type(4))) float f32x4;

constexpr int N_  = 16384;
constexpr int D_  = 1024;
constexpr int E_  = 65536;
constexpr int ET_ = E_ + N_;   // edges incl. self loops
constexpr int H_  = 8;
constexpr int C_  = 512;
constexpr int F_  = 4096;      // H_*C_
constexpr int ZS_ = 48;        // [al_s 0..7 | al_d 8..15 | z0 16..23 | z1 24..31 | zd 32..39 | pad]
constexpr int KSPLIT = 2;
constexpr int NVB = 2048;      // V-build blocks in prep
constexpr int NZB = 960;       // zero blocks in prep (3.75 MB / (256*16B))

// ---------- helpers ----------
DEV unsigned short f2bf(float f){
  unsigned u = __float_as_uint(f);
  unsigned r = u + 0x7FFFu + ((u >> 16) & 1u); // RNE
  return (unsigned short)(r >> 16);
}
DEV float lrelu(float x){ return x >= 0.f ? x : 0.2f * x; }
DEV float waveSum(float v){
  #pragma unroll
  for (int o = 32; o > 0; o >>= 1) v += __shfl_xor(v, o);
  return v;
}
DEV int eSRC(const int* ei, int e){ return e < E_ ? ei[e]      : e - E_; }
DEV int eDST(const int* ei, int e){ return e < E_ ? ei[E_ + e] : e - E_; }

// ---------- kernel 1: prep = zero region + build V (MFMA-B-frag) + cb ----------
// col jj of V: jj=h: W1s_h.a1s[h] | 8+h: W1d_h.a1d[h] | 16+h: W1s_h.W2s[:,0]
//              24+h: W1s_h.W2s[:,1] | 32+h: W1s_h.wd2   (wd2 inline from W2d)
// Vb[((tt*32+kc)*64 + ks*16 + j)*8 + i], tt=jj>>4, j=jj&15, kc=d>>5, ks=(d>>3)&3, i=d&7
__global__ __launch_bounds__(256) void prep(
    const float* __restrict__ W1s, const float* __restrict__ W1d,
    const float* __restrict__ a1s, const float* __restrict__ a1d,
    const float* __restrict__ W2s, const float* __restrict__ W2d,
    const float* __restrict__ a2d, const float* __restrict__ b1,
    unsigned short* __restrict__ Vb, float* __restrict__ cb,
    uint4* __restrict__ zr){
  int t = threadIdx.x;
  int bx = blockIdx.x;
  if (bx < NVB){
    int id = bx * 4 + (t >> 6);            // 0..8191
    int lane = t & 63;
    int d = id >> 3, h = id & 7;
    float a2d0 = a2d[0], a2d1 = a2d[1];
    float sa = 0.f, sb = 0.f, s0 = 0.f, s1 = 0.f, sd = 0.f;
    #pragma unroll
    for (int i = 0; i < C_ / 64; i++){
      int c = i * 64 + lane;
      int gc = h * C_ + c;
      float ws  = W1s[(size_t)d * F_ + gc];
      float wdv = W1d[(size_t)d * F_ + gc];
      sa += ws * a1s[gc]; sb += wdv * a1d[gc];
      float2 w2 = *reinterpret_cast<const float2*>(W2s + (size_t)gc * 2);
      float2 wx = *reinterpret_cast<const float2*>(W2d + (size_t)gc * 2);
      s0 += ws * w2.x; s1 += ws * w2.y;
      sd += ws * (wx.x * a2d0 + wx.y * a2d1);
    }
    sa = waveSum(sa); sb = waveSum(sb);
    s0 = waveSum(s0); s1 = waveSum(s1); sd = waveSum(sd);
    if (lane == 0){
      int kc = d >> 5, ks = (d >> 3) & 3, ii = d & 7;
      auto put = [&](int jj, float v){
        int tt = jj >> 4, j = jj & 15;
        Vb[((size_t)(tt * 32 + kc) * 64 + ks * 16 + j) * 8 + ii] = f2bf(v);
      };
      put(h, sa); put(8 + h, sb); put(16 + h, s0); put(24 + h, s1); put(32 + h, sd);
    }
  } else if (bx == NVB){
    // cb = (b1.W2s[:,0], b1.W2s[:,1], b1.wd2)
    __shared__ float red[3][4];
    int w = t >> 6, lane = t & 63;
    float a2d0 = a2d[0], a2d1 = a2d[1];
    float p0 = 0.f, p1 = 0.f, pd = 0.f;
    for (int k = t; k < F_; k += 256){
      float b = b1[k];
      float2 w2 = *reinterpret_cast<const float2*>(W2s + (size_t)k * 2);
      float2 wx = *reinterpret_cast<const float2*>(W2d + (size_t)k * 2);
      p0 += b * w2.x; p1 += b * w2.y; pd += b * (wx.x * a2d0 + wx.y * a2d1);
    }
    p0 = waveSum(p0); p1 = waveSum(p1); pd = waveSum(pd);
    if (lane == 0){ red[0][w] = p0; red[1][w] = p1; red[2][w] = pd; }
    __syncthreads();
    if (t == 0){
      cb[0] = red[0][0] + red[0][1] + red[0][2] + red[0][3];
      cb[1] = red[1][0] + red[1][1] + red[1][2] + red[1][3];
      cb[2] = red[2][0] + red[2][1] + red[2][2] + red[2][3];
    }
  } else {
    int i = (bx - NVB - 1) * 256 + t;      // 0..245759
    uint4 z = {0u, 0u, 0u, 0u};
    zr[i] = z;
  }
}

// ---------- kernel 2: Z[n][0..47] += x[n] @ V (K-split x2, 4 waves/block) ----------
__global__ __launch_bounds__(256) void node_mfma(const float* __restrict__ X,
                                                 const unsigned short* __restrict__ Vb,
                                                 float* __restrict__ Z){
  int t = threadIdx.x;
  int w = t >> 6, lane = t & 63;
  int ngrp = blockIdx.x * 2 + (w >> 1);
  int kh = w & 1;
  int n0 = ngrp * 16;
  int row = lane & 15, ks = lane >> 4;
  f32x4 ac0 = {0.f,0.f,0.f,0.f}, ac1 = ac0, ac2 = ac0;
  const float* xp = X + (size_t)(n0 + row) * D_ + ks * 8;
  constexpr int KC = 32 / KSPLIT;
  #pragma unroll 2
  for (int kk = 0; kk < KC; kk++){
    int kc = kh * KC + kk;
    float4 xa = *reinterpret_cast<const float4*>(xp + kc * 32);
    float4 xb = *reinterpret_cast<const float4*>(xp + kc * 32 + 4);
    bf16x8 a;
    a[0] = (short)f2bf(xa.x); a[1] = (short)f2bf(xa.y);
    a[2] = (short)f2bf(xa.z); a[3] = (short)f2bf(xa.w);
    a[4] = (short)f2bf(xb.x); a[5] = (short)f2bf(xb.y);
    a[6] = (short)f2bf(xb.z); a[7] = (short)f2bf(xb.w);
    bf16x8 b0 = *reinterpret_cast<const bf16x8*>(&Vb[((size_t)( 0 + kc) * 64 + lane) * 8]);
    bf16x8 b1 = *reinterpret_cast<const bf16x8*>(&Vb[((size_t)(32 + kc) * 64 + lane) * 8]);
    bf16x8 b2 = *reinterpret_cast<const bf16x8*>(&Vb[((size_t)(64 + kc) * 64 + lane) * 8]);
    ac0 = __builtin_amdgcn_mfma_f32_16x16x32_bf16(a, b0, ac0, 0, 0, 0);
    ac1 = __builtin_amdgcn_mfma_f32_16x16x32_bf16(a, b1, ac1, 0, 0, 0);
    ac2 = __builtin_amdgcn_mfma_f32_16x16x32_bf16(a, b2, ac2, 0, 0, 0);
  }
  #pragma unroll
  for (int r = 0; r < 4; r++){
    int n = n0 + ks * 4 + r;
    atomicAdd(&Z[(size_t)n * ZS_ +  0 + row], ac0[r]);
    atomicAdd(&Z[(size_t)n * ZS_ + 16 + row], ac1[r]);
    atomicAdd(&Z[(size_t)n * ZS_ + 32 + row], ac2[r]);
  }
}

// ---------- kernel 3: layer-1 edge softmax (per-edge, vectorized) ----------
__global__ void edge_exp1(const int* __restrict__ ei, const float* __restrict__ Z,
                          float* __restrict__ expv, float* __restrict__ den1){
  int e = blockIdx.x * blockDim.x + threadIdx.x;
  if (e >= ET_) return;
  int s = eSRC(ei, e), d = eDST(ei, e);
  const float4* zs = reinterpret_cast<const float4*>(Z + (size_t)s * ZS_);
  const float4* zd = reinterpret_cast<const float4*>(Z + (size_t)d * ZS_ + 8);
  float4 sa0 = zs[0], sa1 = zs[1];
  float4 da0 = zd[0], da1 = zd[1];
  float4 ev0, ev1;
  ev0.x = expf(lrelu(sa0.x + da0.x)); ev0.y = expf(lrelu(sa0.y + da0.y));
  ev0.z = expf(lrelu(sa0.z + da0.z)); ev0.w = expf(lrelu(sa0.w + da0.w));
  ev1.x = expf(lrelu(sa1.x + da1.x)); ev1.y = expf(lrelu(sa1.y + da1.y));
  ev1.z = expf(lrelu(sa1.z + da1.z)); ev1.w = expf(lrelu(sa1.w + da1.w));
  float4* ep = reinterpret_cast<float4*>(expv + (size_t)e * 8);
  ep[0] = ev0; ep[1] = ev1;
  float* dn = den1 + (size_t)d * 8;
  atomicAdd(dn + 0, ev0.x); atomicAdd(dn + 1, ev0.y);
  atomicAdd(dn + 2, ev0.z); atomicAdd(dn + 3, ev0.w);
  atomicAdd(dn + 4, ev1.x); atomicAdd(dn + 5, ev1.y);
  atomicAdd(dn + 6, ev1.z); atomicAdd(dn + 7, ev1.w);
}

// ---------- kernel 4: aggregate z over edges ----------
__global__ void agg_z(const int* __restrict__ ei, const float* __restrict__ Z,
                      const float* __restrict__ expv, const float* __restrict__ den1,
                      float* __restrict__ s0a, float* __restrict__ s1a,
                      float* __restrict__ sda){
  int e = blockIdx.x * blockDim.x + threadIdx.x;
  if (e >= ET_) return;
  int s = eSRC(ei, e), d = eDST(ei, e);
  float4 ev0 = *reinterpret_cast<const float4*>(expv + (size_t)e * 8);
  float4 ev1 = *reinterpret_cast<const float4*>(expv + (size_t)e * 8 + 4);
  float4 dn0 = *reinterpret_cast<const float4*>(den1 + (size_t)d * 8);
  float4 dn1 = *reinterpret_cast<const float4*>(den1 + (size_t)d * 8 + 4);
  float al[8];
  al[0] = ev0.x / (dn0.x + 1e-16f); al[1] = ev0.y / (dn0.y + 1e-16f);
  al[2] = ev0.z / (dn0.z + 1e-16f); al[3] = ev0.w / (dn0.w + 1e-16f);
  al[4] = ev1.x / (dn1.x + 1e-16f); al[5] = ev1.y / (dn1.y + 1e-16f);
  al[6] = ev1.z / (dn1.z + 1e-16f); al[7] = ev1.w / (dn1.w + 1e-16f);
  const float* zp = Z + (size_t)s * ZS_;
  float4 z0a = *reinterpret_cast<const float4*>(zp + 16);
  float4 z0b = *reinterpret_cast<const float4*>(zp + 20);
  float4 z1a = *reinterpret_cast<const float4*>(zp + 24);
  float4 z1b = *reinterpret_cast<const float4*>(zp + 28);
  float4 zda = *reinterpret_cast<const float4*>(zp + 32);
  float4 zdb = *reinterpret_cast<const float4*>(zp + 36);
  float p0 = al[0]*z0a.x + al[1]*z0a.y + al[2]*z0a.z + al[3]*z0a.w
           + al[4]*z0b.x + al[5]*z0b.y + al[6]*z0b.z + al[7]*z0b.w;
  float p1 = al[0]*z1a.x + al[1]*z1a.y + al[2]*z1a.z + al[3]*z1a.w
           + al[4]*z1b.x + al[5]*z1b.y + al[6]*z1b.z + al[7]*z1b.w;
  float pd = al[0]*zda.x + al[1]*zda.y + al[2]*zda.z + al[3]*zda.w
           + al[4]*zdb.x + al[5]*zdb.y + al[6]*zdb.z + al[7]*zdb.w;
  atomicAdd(&s0a[d], p0);
  atomicAdd(&s1a[d], p1);
  atomicAdd(&sda[d], pd);
}

// ---------- kernel 5: layer-2 edge softmax (logits inline) + out init ----------
__global__ void edge_exp2(const int* __restrict__ ei, const float* __restrict__ s0a,
                          const float* __restrict__ s1a, const float* __restrict__ sda,
                          const float* __restrict__ cb, const float* __restrict__ a2s,
                          const float* __restrict__ b2,
                          float* __restrict__ expv2, float* __restrict__ den2,
                          float* __restrict__ out){
  int e = blockIdx.x * blockDim.x + threadIdx.x;
  if (e >= ET_) return;
  int s = eSRC(ei, e), d = eDST(ei, e);
  float als = (s0a[s] + cb[0]) * a2s[0] + (s1a[s] + cb[1]) * a2s[1];
  float ald = sda[d] + cb[2];
  float ev = expf(lrelu(als + ald));
  expv2[e] = ev;
  atomicAdd(&den2[d], ev);
  if (e < N_){ out[2 * e] = b2[0]; out[2 * e + 1] = b2[1]; }
}

// ---------- kernel 6: layer-2 aggregation -> output ----------
__global__ void aggregate2(const int* __restrict__ ei, const float* __restrict__ expv2,
                           const float* __restrict__ den2, const float* __restrict__ s0a,
                           const float* __restrict__ s1a, const float* __restrict__ cb,
                           float* __restrict__ out){
  int e = blockIdx.x * blockDim.x + threadIdx.x;
  if (e >= ET_) return;
  int s = eSRC(ei, e), d = eDST(ei, e);
  float a = expv2[e] / (den2[d] + 1e-16f);
  atomicAdd(&out[2 * d],     a * (s0a[s] + cb[0]));
  atomicAdd(&out[2 * d + 1], a * (s1a[s] + cb[1]));
}

// ---------- host ----------
extern "C" void kernel_launch(void* const* d_in, const int* in_sizes, int n_in,
                              void* d_out, int out_size, void* d_ws, size_t ws_size,
                              hipStream_t stream){
  const float* x   = (const float*)d_in[0];
  const int*   ei  = (const int*)  d_in[1];
  const float* W1s = (const float*)d_in[2];
  const float* W1d = (const float*)d_in[3];
  const float* a1s = (const float*)d_in[4];
  const float* a1d = (const float*)d_in[5];
  const float* b1  = (const float*)d_in[6];
  const float* W2s = (const float*)d_in[7];
  const float* W2d = (const float*)d_in[8];
  const float* a2s = (const float*)d_in[9];
  const float* a2d = (const float*)d_in[10];
  const float* b2  = (const float*)d_in[11];
  float* out = (float*)d_out;

  char* p = (char*)d_ws;
  auto alloc = [&](size_t bytes) -> void* {
    void* r = (void*)p;
    p += (bytes + 255) & ~(size_t)255;
    return r;
  };
  // ---- contiguous zero region (3.75 MB = NZB*256*16 B) ----
  float* Z     = (float*)alloc((size_t)N_ * ZS_ * 4);      // 3 MB
  float* den1  = (float*)alloc((size_t)N_ * H_ * 4);       // 512 KB
  float* den2  = (float*)alloc((size_t)N_ * 4);            // 64 KB
  float* s0a   = (float*)alloc((size_t)N_ * 4);
  float* s1a   = (float*)alloc((size_t)N_ * 4);
  float* sda   = (float*)alloc((size_t)N_ * 4);
  // ---- end zero region ----
  unsigned short* Vb = (unsigned short*)alloc((size_t)3 * 32 * 64 * 8 * 2); // 96 KB (pad cols never read)
  float* cb    = (float*)alloc(256);
  float* expv1 = (float*)alloc((size_t)ET_ * H_ * 4);      // 2.6 MB
  float* expv2 = (float*)alloc((size_t)ET_ * 4);

  prep<<<dim3(NVB + 1 + NZB), dim3(256), 0, stream>>>(W1s, W1d, a1s, a1d, W2s, W2d,
                                                      a2d, b1, Vb, cb, (uint4*)Z);
  node_mfma<<<dim3(N_ / 32), dim3(256), 0, stream>>>(x, Vb, Z);
  edge_exp1<<<dim3((ET_ + 255) / 256), dim3(256), 0, stream>>>(ei, Z, expv1, den1);
  agg_z<<<dim3(ET_ / 256), dim3(256), 0, stream>>>(ei, Z, expv1, den1, s0a, s1a, sda);
  edge_exp2<<<dim3(ET_ / 256), dim3(256), 0, stream>>>(ei, s0a, s1a, sda, cb, a2s, b2,
                                                       expv2, den2, out);
  aggregate2<<<dim3(ET_ / 256), dim3(256), 0, stream>>>(ei, expv2, den2, s0a, s1a, cb, out);
}

// Round 8
// 73.888 us; speedup vs baseline: 1.3401x; 1.3401x over previous
//
#include <hip/hip_runtime.h>
#include <cstdint>
#include <cstddef>

#define DEV __device__ __forceinline__

typedef __attribute__((ext_vector_type(8))) short bf16x8;
typedef __attribute__((ext_vector_type(4))) float f32x4;

constexpr int N_  = 16384;
constexpr int D_  = 1024;
constexpr int E_  = 65536;
constexpr int ET_ = E_ + N_;   // edges incl. self loops
constexpr int H_  = 8;
constexpr int C_  = 512;
constexpr int F_  = 4096;      // H_*C_
constexpr int ZS_ = 48;        // [al_s 0..7 | al_d 8..15 | z0 16..23 | z1 24..31 | zd 32..39 | pad]
constexpr int KSPLIT = 2;

// ---------- helpers ----------
DEV unsigned short f2bf(float f){
  unsigned u = __float_as_uint(f);
  unsigned r = u + 0x7FFFu + ((u >> 16) & 1u); // RNE
  return (unsigned short)(r >> 16);
}
DEV float lrelu(float x){ return x >= 0.f ? x : 0.2f * x; }
DEV float waveSum(float v){
  #pragma unroll
  for (int o = 32; o > 0; o >>= 1) v += __shfl_xor(v, o);
  return v;
}
DEV int eSRC(const int* ei, int e){ return e < E_ ? ei[e]      : e - E_; }
DEV int eDST(const int* ei, int e){ return e < E_ ? ei[E_ + e] : e - E_; }

// ---------- kernel 1: zero contiguous region + build wd2 ----------
__global__ void init_all(uint4* __restrict__ zr, int n16,
                         const float* __restrict__ W2d, const float* __restrict__ a2d,
                         float* __restrict__ wd2){
  int i = blockIdx.x * blockDim.x + threadIdx.x;
  if (i < n16){ uint4 z = {0u,0u,0u,0u}; zr[i] = z; }
  if (i < F_) wd2[i] = W2d[i * 2] * a2d[0] + W2d[i * 2 + 1] * a2d[1];
}

// ---------- kernel 2: build V [1024 x 40 used cols] in MFMA-B-frag order + cb ----------
// col jj: jj=h: W1s_h.a1s[h] | 8+h: W1d_h.a1d[h] | 16+h: W1s_h.W2s[:,0]
//         24+h: W1s_h.W2s[:,1] | 32+h: W1s_h.wd2
// Vb[((tt*32+kc)*64 + ks*16 + j)*8 + i], tt=jj>>4, j=jj&15, kc=d>>5, ks=(d>>3)&3, i=d&7
__global__ __launch_bounds__(256) void build_Vcb(
    const float* __restrict__ W1s, const float* __restrict__ W1d,
    const float* __restrict__ a1s, const float* __restrict__ a1d,
    const float* __restrict__ W2s, const float* __restrict__ wd2,
    const float* __restrict__ b1,
    unsigned short* __restrict__ Vb, float* __restrict__ cb){
  int t = threadIdx.x;
  if (blockIdx.x == D_ * H_ / 4){
    // cb = (b1.W2s[:,0], b1.W2s[:,1], b1.wd2)
    __shared__ float red[3][4];
    int w = t >> 6, lane = t & 63;
    float p0 = 0.f, p1 = 0.f, pd = 0.f;
    for (int k = t; k < F_; k += 256){
      float b = b1[k];
      p0 += b * W2s[k * 2]; p1 += b * W2s[k * 2 + 1]; pd += b * wd2[k];
    }
    p0 = waveSum(p0); p1 = waveSum(p1); pd = waveSum(pd);
    if (lane == 0){ red[0][w] = p0; red[1][w] = p1; red[2][w] = pd; }
    __syncthreads();
    if (t == 0){
      cb[0] = red[0][0] + red[0][1] + red[0][2] + red[0][3];
      cb[1] = red[1][0] + red[1][1] + red[1][2] + red[1][3];
      cb[2] = red[2][0] + red[2][1] + red[2][2] + red[2][3];
    }
    return;
  }
  int id = blockIdx.x * 4 + (t >> 6);      // 0..8191
  int lane = t & 63;
  int d = id >> 3, h = id & 7;
  float sa = 0.f, sb = 0.f, s0 = 0.f, s1 = 0.f, sd = 0.f;
  #pragma unroll
  for (int i = 0; i < C_ / 64; i++){
    int c = i * 64 + lane;
    int gc = h * C_ + c;
    float ws  = W1s[(size_t)d * F_ + gc];
    float wdv = W1d[(size_t)d * F_ + gc];
    sa += ws * a1s[gc]; sb += wdv * a1d[gc];
    float2 w2 = *reinterpret_cast<const float2*>(W2s + (size_t)gc * 2);
    s0 += ws * w2.x; s1 += ws * w2.y; sd += ws * wd2[gc];
  }
  sa = waveSum(sa); sb = waveSum(sb);
  s0 = waveSum(s0); s1 = waveSum(s1); sd = waveSum(sd);
  if (lane == 0){
    int kc = d >> 5, ks = (d >> 3) & 3, ii = d & 7;
    auto put = [&](int jj, float v){
      int tt = jj >> 4, j = jj & 15;
      Vb[((size_t)(tt * 32 + kc) * 64 + ks * 16 + j) * 8 + ii] = f2bf(v);
    };
    put(h, sa); put(8 + h, sb); put(16 + h, s0); put(24 + h, s1); put(32 + h, sd);
  }
}

// ---------- kernel 3: Z[n][0..47] += x[n] @ V (half-K per wave, K-split x2) ----------
__global__ __launch_bounds__(64) void node_mfma(const float* __restrict__ X,
                                                const unsigned short* __restrict__ Vb,
                                                float* __restrict__ Z){
  int lane = threadIdx.x;
  int n0 = blockIdx.x * 16;
  int kh = blockIdx.y;                       // 0..KSPLIT-1
  int row = lane & 15, ks = lane >> 4;
  f32x4 ac0 = {0.f,0.f,0.f,0.f}, ac1 = ac0, ac2 = ac0;
  const float* xp = X + (size_t)(n0 + row) * D_ + ks * 8;
  constexpr int KC = 32 / KSPLIT;
  #pragma unroll 2
  for (int kk = 0; kk < KC; kk++){
    int kc = kh * KC + kk;
    float4 xa = *reinterpret_cast<const float4*>(xp + kc * 32);
    float4 xb = *reinterpret_cast<const float4*>(xp + kc * 32 + 4);
    bf16x8 a;
    a[0] = (short)f2bf(xa.x); a[1] = (short)f2bf(xa.y);
    a[2] = (short)f2bf(xa.z); a[3] = (short)f2bf(xa.w);
    a[4] = (short)f2bf(xb.x); a[5] = (short)f2bf(xb.y);
    a[6] = (short)f2bf(xb.z); a[7] = (short)f2bf(xb.w);
    bf16x8 b0 = *reinterpret_cast<const bf16x8*>(&Vb[((size_t)( 0 + kc) * 64 + lane) * 8]);
    bf16x8 b1 = *reinterpret_cast<const bf16x8*>(&Vb[((size_t)(32 + kc) * 64 + lane) * 8]);
    bf16x8 b2 = *reinterpret_cast<const bf16x8*>(&Vb[((size_t)(64 + kc) * 64 + lane) * 8]);
    ac0 = __builtin_amdgcn_mfma_f32_16x16x32_bf16(a, b0, ac0, 0, 0, 0);
    ac1 = __builtin_amdgcn_mfma_f32_16x16x32_bf16(a, b1, ac1, 0, 0, 0);
    ac2 = __builtin_amdgcn_mfma_f32_16x16x32_bf16(a, b2, ac2, 0, 0, 0);
  }
  #pragma unroll
  for (int r = 0; r < 4; r++){
    int n = n0 + ks * 4 + r;
    atomicAdd(&Z[(size_t)n * ZS_ +  0 + row], ac0[r]);
    atomicAdd(&Z[(size_t)n * ZS_ + 16 + row], ac1[r]);
    atomicAdd(&Z[(size_t)n * ZS_ + 32 + row], ac2[r]);
  }
}

// ---------- kernel 4: layer-1 fused exp + weighted accumulate (one pass) ----------
// per (edge, head): ev = exp(lrelu(al_s[s,h]+al_d[d,h]));
// den1[d,h]+=ev; a0[d,h]+=ev*z0[s,h]; a1[d,h]+=ev*z1[s,h]; ad[d,h]+=ev*zd[s,h]
__global__ void edge1(const int* __restrict__ ei, const float* __restrict__ Z,
                      float* __restrict__ den1, float* __restrict__ a0,
                      float* __restrict__ a1, float* __restrict__ ad){
  int t = blockIdx.x * blockDim.x + threadIdx.x;
  if (t >= ET_ * H_) return;
  int e = t >> 3, h = t & 7;
  int s = eSRC(ei, e), d = eDST(ei, e);
  const float* zs = Z + (size_t)s * ZS_;
  float ev = expf(lrelu(zs[h] + Z[(size_t)d * ZS_ + 8 + h]));
  int o = d * 8 + h;
  atomicAdd(&den1[o], ev);
  atomicAdd(&a0[o], ev * zs[16 + h]);
  atomicAdd(&a1[o], ev * zs[24 + h]);
  atomicAdd(&ad[o], ev * zs[32 + h]);
}

// ---------- kernel 5: per-node head-division + layer-2 logits (packed float4) ----------
// Pn[n] = { als2, s0b, s1b, ald2 }
__global__ void node_mid(const float* __restrict__ den1, const float* __restrict__ a0,
                         const float* __restrict__ a1, const float* __restrict__ ad,
                         const float* __restrict__ cb, const float* __restrict__ a2s,
                         float4* __restrict__ Pn){
  int n = blockIdx.x * blockDim.x + threadIdx.x;
  if (n >= N_) return;
  float v0 = 0.f, v1 = 0.f, vd = 0.f;
  #pragma unroll
  for (int h = 0; h < 8; h++){
    float inv = 1.f / (den1[n * 8 + h] + 1e-16f);
    v0 += a0[n * 8 + h] * inv;
    v1 += a1[n * 8 + h] * inv;
    vd += ad[n * 8 + h] * inv;
  }
  v0 += cb[0]; v1 += cb[1]; vd += cb[2];
  float4 r;
  r.x = v0 * a2s[0] + v1 * a2s[1];   // als2
  r.y = v0; r.z = v1;                // s0b, s1b
  r.w = vd;                          // ald2
  Pn[n] = r;
}

// ---------- kernel 6: layer-2 fused exp + weighted accumulate ----------
__global__ void edge2(const int* __restrict__ ei, const float4* __restrict__ Pn,
                      float* __restrict__ den2, float* __restrict__ o0,
                      float* __restrict__ o1){
  int e = blockIdx.x * blockDim.x + threadIdx.x;
  if (e >= ET_) return;
  int s = eSRC(ei, e), d = eDST(ei, e);
  float4 ps = Pn[s];
  float ald = Pn[d].w;
  float ev = expf(lrelu(ps.x + ald));
  atomicAdd(&den2[d], ev);
  atomicAdd(&o0[d], ev * ps.y);
  atomicAdd(&o1[d], ev * ps.z);
}

// ---------- kernel 7: final division + bias -> out ----------
__global__ void node_out(const float* __restrict__ den2, const float* __restrict__ o0,
                         const float* __restrict__ o1, const float* __restrict__ b2,
                         float* __restrict__ out){
  int n = blockIdx.x * blockDim.x + threadIdx.x;
  if (n >= N_) return;
  float inv = 1.f / (den2[n] + 1e-16f);
  out[2 * n]     = o0[n] * inv + b2[0];
  out[2 * n + 1] = o1[n] * inv + b2[1];
}

// ---------- host ----------
extern "C" void kernel_launch(void* const* d_in, const int* in_sizes, int n_in,
                              void* d_out, int out_size, void* d_ws, size_t ws_size,
                              hipStream_t stream){
  const float* x   = (const float*)d_in[0];
  const int*   ei  = (const int*)  d_in[1];
  const float* W1s = (const float*)d_in[2];
  const float* W1d = (const float*)d_in[3];
  const float* a1s = (const float*)d_in[4];
  const float* a1d = (const float*)d_in[5];
  const float* b1  = (const float*)d_in[6];
  const float* W2s = (const float*)d_in[7];
  const float* W2d = (const float*)d_in[8];
  const float* a2s = (const float*)d_in[9];
  const float* a2d = (const float*)d_in[10];
  const float* b2  = (const float*)d_in[11];
  float* out = (float*)d_out;

  char* p = (char*)d_ws;
  auto alloc = [&](size_t bytes) -> void* {
    void* r = (void*)p;
    p += (bytes + 255) & ~(size_t)255;
    return r;
  };
  // ---- contiguous zero region ----
  float* Z     = (float*)alloc((size_t)N_ * ZS_ * 4);      // 3 MB
  float* den1  = (float*)alloc((size_t)N_ * H_ * 4);       // 512 KB
  float* a0    = (float*)alloc((size_t)N_ * H_ * 4);
  float* a1    = (float*)alloc((size_t)N_ * H_ * 4);
  float* ad    = (float*)alloc((size_t)N_ * H_ * 4);
  float* den2  = (float*)alloc((size_t)N_ * 4);            // 64 KB
  float* o0    = (float*)alloc((size_t)N_ * 4);
  float* o1    = (float*)alloc((size_t)N_ * 4);
  unsigned short* Vb = (unsigned short*)alloc((size_t)3 * 32 * 64 * 8 * 2); // 96 KB
  // ---- end zero region ----
  float* wd2   = (float*)alloc((size_t)F_ * 4);
  float* cb    = (float*)alloc(256);
  float4* Pn   = (float4*)alloc((size_t)N_ * 16);

  size_t zrBytes = (size_t)((char*)wd2 - (char*)Z);
  int n16 = (int)(zrBytes / 16);
  int g1 = (int)((((n16 > F_) ? n16 : F_) + 255) / 256);

  init_all<<<dim3(g1), dim3(256), 0, stream>>>((uint4*)Z, n16, W2d, a2d, wd2);
  build_Vcb<<<dim3(D_ * H_ / 4 + 1), dim3(256), 0, stream>>>(W1s, W1d, a1s, a1d,
                                                             W2s, wd2, b1, Vb, cb);
  node_mfma<<<dim3(N_ / 16, KSPLIT), dim3(64), 0, stream>>>(x, Vb, Z);
  edge1<<<dim3(ET_ * H_ / 256), dim3(256), 0, stream>>>(ei, Z, den1, a0, a1, ad);
  node_mid<<<dim3(N_ / 256), dim3(256), 0, stream>>>(den1, a0, a1, ad, cb, a2s, Pn);
  edge2<<<dim3(ET_ / 256), dim3(256), 0, stream>>>(ei, Pn, den2, o0, o1);
  node_out<<<dim3(N_ / 256), dim3(256), 0, stream>>>(den2, o0, o1, b2, out);
}

// Round 9
// 71.448 us; speedup vs baseline: 1.3859x; 1.0341x over previous
//
#include <hip/hip_runtime.h>
#include <cstdint>
#include <cstddef>

#define DEV __device__ __forceinline__

typedef __attribute__((ext_vector_type(8))) short bf16x8;
typedef __attribute__((ext_vector_type(4))) float f32x4;

constexpr int N_  = 16384;
constexpr int D_  = 1024;
constexpr int E_  = 65536;
constexpr int ET_ = E_ + N_;   // edges incl. self loops
constexpr int H_  = 8;
constexpr int C_  = 512;
constexpr int F_  = 4096;      // H_*C_
constexpr int ZS_ = 48;        // [al_s 0..7 | al_d 8..15 | z0 16..23 | z1 24..31 | zd 32..39 | pad]
constexpr int KSPLIT = 4;
constexpr int NVB = 2048;      // V-build blocks in prep

// ---------- helpers ----------
DEV unsigned short f2bf(float f){
  unsigned u = __float_as_uint(f);
  unsigned r = u + 0x7FFFu + ((u >> 16) & 1u); // RNE
  return (unsigned short)(r >> 16);
}
DEV float lrelu(float x){ return x >= 0.f ? x : 0.2f * x; }
DEV float waveSum(float v){
  #pragma unroll
  for (int o = 32; o > 0; o >>= 1) v += __shfl_xor(v, o);
  return v;
}
DEV int eSRC(const int* ei, int e){ return e < E_ ? ei[e]      : e - E_; }
DEV int eDST(const int* ei, int e){ return e < E_ ? ei[E_ + e] : e - E_; }

// ---------- kernel 1: prep = build V (MFMA-B-frag) + cb + zero region ----------
// col jj of V: jj=h: W1s_h.a1s[h] | 8+h: W1d_h.a1d[h] | 16+h: W1s_h.W2s[:,0]
//              24+h: W1s_h.W2s[:,1] | 32+h: W1s_h.wd2  (wd2 inline from W2d)
// Vb[((tt*32+kc)*64 + ks*16 + j)*8 + i], tt=jj>>4, j=jj&15, kc=d>>5, ks=(d>>3)&3, i=d&7
__global__ __launch_bounds__(256) void prep(
    const float* __restrict__ W1s, const float* __restrict__ W1d,
    const float* __restrict__ a1s, const float* __restrict__ a1d,
    const float* __restrict__ W2s, const float* __restrict__ W2d,
    const float* __restrict__ a2d, const float* __restrict__ b1,
    unsigned short* __restrict__ Vb, float* __restrict__ cb,
    uint4* __restrict__ zr, int n16){
  int t = threadIdx.x;
  int bx = blockIdx.x;
  if (bx < NVB){
    int id = bx * 4 + (t >> 6);            // 0..8191
    int lane = t & 63;
    int d = id >> 3, h = id & 7;
    float a2d0 = a2d[0], a2d1 = a2d[1];
    float sa = 0.f, sb = 0.f, s0 = 0.f, s1 = 0.f, sd = 0.f;
    #pragma unroll
    for (int i = 0; i < C_ / 64; i++){
      int c = i * 64 + lane;
      int gc = h * C_ + c;
      float ws  = W1s[(size_t)d * F_ + gc];
      float wdv = W1d[(size_t)d * F_ + gc];
      sa += ws * a1s[gc]; sb += wdv * a1d[gc];
      float2 w2 = *reinterpret_cast<const float2*>(W2s + (size_t)gc * 2);
      float2 wx = *reinterpret_cast<const float2*>(W2d + (size_t)gc * 2);
      s0 += ws * w2.x; s1 += ws * w2.y;
      sd += ws * (wx.x * a2d0 + wx.y * a2d1);
    }
    sa = waveSum(sa); sb = waveSum(sb);
    s0 = waveSum(s0); s1 = waveSum(s1); sd = waveSum(sd);
    if (lane == 0){
      int kc = d >> 5, ks = (d >> 3) & 3, ii = d & 7;
      auto put = [&](int jj, float v){
        int tt = jj >> 4, j = jj & 15;
        Vb[((size_t)(tt * 32 + kc) * 64 + ks * 16 + j) * 8 + ii] = f2bf(v);
      };
      put(h, sa); put(8 + h, sb); put(16 + h, s0); put(24 + h, s1); put(32 + h, sd);
    }
  } else if (bx == NVB){
    // cb = (b1.W2s[:,0], b1.W2s[:,1], b1.wd2)
    __shared__ float red[3][4];
    int w = t >> 6, lane = t & 63;
    float a2d0 = a2d[0], a2d1 = a2d[1];
    float p0 = 0.f, p1 = 0.f, pd = 0.f;
    for (int k = t; k < F_; k += 256){
      float b = b1[k];
      float2 w2 = *reinterpret_cast<const float2*>(W2s + (size_t)k * 2);
      float2 wx = *reinterpret_cast<const float2*>(W2d + (size_t)k * 2);
      p0 += b * w2.x; p1 += b * w2.y; pd += b * (wx.x * a2d0 + wx.y * a2d1);
    }
    p0 = waveSum(p0); p1 = waveSum(p1); pd = waveSum(pd);
    if (lane == 0){ red[0][w] = p0; red[1][w] = p1; red[2][w] = pd; }
    __syncthreads();
    if (t == 0){
      cb[0] = red[0][0] + red[0][1] + red[0][2] + red[0][3];
      cb[1] = red[1][0] + red[1][1] + red[1][2] + red[1][3];
      cb[2] = red[2][0] + red[2][1] + red[2][2] + red[2][3];
    }
  } else {
    int i = (bx - NVB - 1) * 256 + t;
    if (i < n16){ uint4 z = {0u, 0u, 0u, 0u}; zr[i] = z; }
  }
}

// ---------- kernel 2: Z[n][0..47] += x[n] @ V (K-split x4, 1 wave/block) ----------
__global__ __launch_bounds__(64) void node_mfma(const float* __restrict__ X,
                                                const unsigned short* __restrict__ Vb,
                                                float* __restrict__ Z){
  int lane = threadIdx.x;
  int n0 = blockIdx.x * 16;
  int kh = blockIdx.y;                       // 0..KSPLIT-1
  int row = lane & 15, ks = lane >> 4;
  f32x4 ac0 = {0.f,0.f,0.f,0.f}, ac1 = ac0, ac2 = ac0;
  const float* xp = X + (size_t)(n0 + row) * D_ + ks * 8;
  constexpr int KC = 32 / KSPLIT;
  #pragma unroll 2
  for (int kk = 0; kk < KC; kk++){
    int kc = kh * KC + kk;
    float4 xa = *reinterpret_cast<const float4*>(xp + kc * 32);
    float4 xb = *reinterpret_cast<const float4*>(xp + kc * 32 + 4);
    bf16x8 a;
    a[0] = (short)f2bf(xa.x); a[1] = (short)f2bf(xa.y);
    a[2] = (short)f2bf(xa.z); a[3] = (short)f2bf(xa.w);
    a[4] = (short)f2bf(xb.x); a[5] = (short)f2bf(xb.y);
    a[6] = (short)f2bf(xb.z); a[7] = (short)f2bf(xb.w);
    bf16x8 b0 = *reinterpret_cast<const bf16x8*>(&Vb[((size_t)( 0 + kc) * 64 + lane) * 8]);
    bf16x8 b1 = *reinterpret_cast<const bf16x8*>(&Vb[((size_t)(32 + kc) * 64 + lane) * 8]);
    bf16x8 b2 = *reinterpret_cast<const bf16x8*>(&Vb[((size_t)(64 + kc) * 64 + lane) * 8]);
    ac0 = __builtin_amdgcn_mfma_f32_16x16x32_bf16(a, b0, ac0, 0, 0, 0);
    ac1 = __builtin_amdgcn_mfma_f32_16x16x32_bf16(a, b1, ac1, 0, 0, 0);
    ac2 = __builtin_amdgcn_mfma_f32_16x16x32_bf16(a, b2, ac2, 0, 0, 0);
  }
  #pragma unroll
  for (int r = 0; r < 4; r++){
    int n = n0 + ks * 4 + r;
    atomicAdd(&Z[(size_t)n * ZS_ +  0 + row], ac0[r]);
    atomicAdd(&Z[(size_t)n * ZS_ + 16 + row], ac1[r]);
    atomicAdd(&Z[(size_t)n * ZS_ + 32 + row], ac2[r]);
  }
}

// ---------- kernel 3: layer-1 fused exp + weighted accumulate ----------
__global__ void edge1(const int* __restrict__ ei, const float* __restrict__ Z,
                      float* __restrict__ den1, float* __restrict__ a0,
                      float* __restrict__ a1, float* __restrict__ ad){
  int t = blockIdx.x * blockDim.x + threadIdx.x;
  if (t >= ET_ * H_) return;
  int e = t >> 3, h = t & 7;
  int s = eSRC(ei, e), d = eDST(ei, e);
  const float* zs = Z + (size_t)s * ZS_;
  float ev = expf(lrelu(zs[h] + Z[(size_t)d * ZS_ + 8 + h]));
  int o = d * 8 + h;
  atomicAdd(&den1[o], ev);
  atomicAdd(&a0[o], ev * zs[16 + h]);
  atomicAdd(&a1[o], ev * zs[24 + h]);
  atomicAdd(&ad[o], ev * zs[32 + h]);
}

// ---------- kernel 4: layer-2 fused (per-edge recompute of node mids) ----------
__global__ void edge2(const int* __restrict__ ei, const float* __restrict__ den1,
                      const float* __restrict__ a0, const float* __restrict__ a1,
                      const float* __restrict__ ad, const float* __restrict__ cb,
                      const float* __restrict__ a2s,
                      float* __restrict__ den2, float* __restrict__ o0,
                      float* __restrict__ o1){
  int e = blockIdx.x * blockDim.x + threadIdx.x;
  if (e >= ET_) return;
  int s = eSRC(ei, e), d = eDST(ei, e);
  // src side: v0, v1
  float4 dsa = *reinterpret_cast<const float4*>(den1 + (size_t)s * 8);
  float4 dsb = *reinterpret_cast<const float4*>(den1 + (size_t)s * 8 + 4);
  float4 a0a = *reinterpret_cast<const float4*>(a0 + (size_t)s * 8);
  float4 a0b = *reinterpret_cast<const float4*>(a0 + (size_t)s * 8 + 4);
  float4 a1a = *reinterpret_cast<const float4*>(a1 + (size_t)s * 8);
  float4 a1b = *reinterpret_cast<const float4*>(a1 + (size_t)s * 8 + 4);
  float i0 = 1.f/(dsa.x+1e-16f), i1 = 1.f/(dsa.y+1e-16f);
  float i2 = 1.f/(dsa.z+1e-16f), i3 = 1.f/(dsa.w+1e-16f);
  float i4 = 1.f/(dsb.x+1e-16f), i5 = 1.f/(dsb.y+1e-16f);
  float i6 = 1.f/(dsb.z+1e-16f), i7 = 1.f/(dsb.w+1e-16f);
  float v0 = cb[0] + a0a.x*i0 + a0a.y*i1 + a0a.z*i2 + a0a.w*i3
                   + a0b.x*i4 + a0b.y*i5 + a0b.z*i6 + a0b.w*i7;
  float v1 = cb[1] + a1a.x*i0 + a1a.y*i1 + a1a.z*i2 + a1a.w*i3
                   + a1b.x*i4 + a1b.y*i5 + a1b.z*i6 + a1b.w*i7;
  // dst side: vd
  float4 dda = *reinterpret_cast<const float4*>(den1 + (size_t)d * 8);
  float4 ddb = *reinterpret_cast<const float4*>(den1 + (size_t)d * 8 + 4);
  float4 ada = *reinterpret_cast<const float4*>(ad + (size_t)d * 8);
  float4 adb = *reinterpret_cast<const float4*>(ad + (size_t)d * 8 + 4);
  float vd = cb[2] + ada.x/(dda.x+1e-16f) + ada.y/(dda.y+1e-16f)
                   + ada.z/(dda.z+1e-16f) + ada.w/(dda.w+1e-16f)
                   + adb.x/(ddb.x+1e-16f) + adb.y/(ddb.y+1e-16f)
                   + adb.z/(ddb.z+1e-16f) + adb.w/(ddb.w+1e-16f);
  float als = v0 * a2s[0] + v1 * a2s[1];
  float ev = expf(lrelu(als + vd));
  atomicAdd(&den2[d], ev);
  atomicAdd(&o0[d], ev * v0);
  atomicAdd(&o1[d], ev * v1);
}

// ---------- kernel 5: final division + bias -> out ----------
__global__ void node_out(const float* __restrict__ den2, const float* __restrict__ o0,
                         const float* __restrict__ o1, const float* __restrict__ b2,
                         float* __restrict__ out){
  int n = blockIdx.x * blockDim.x + threadIdx.x;
  if (n >= N_) return;
  float inv = 1.f / (den2[n] + 1e-16f);
  out[2 * n]     = o0[n] * inv + b2[0];
  out[2 * n + 1] = o1[n] * inv + b2[1];
}

// ---------- host ----------
extern "C" void kernel_launch(void* const* d_in, const int* in_sizes, int n_in,
                              void* d_out, int out_size, void* d_ws, size_t ws_size,
                              hipStream_t stream){
  const float* x   = (const float*)d_in[0];
  const int*   ei  = (const int*)  d_in[1];
  const float* W1s = (const float*)d_in[2];
  const float* W1d = (const float*)d_in[3];
  const float* a1s = (const float*)d_in[4];
  const float* a1d = (const float*)d_in[5];
  const float* b1  = (const float*)d_in[6];
  const float* W2s = (const float*)d_in[7];
  const float* W2d = (const float*)d_in[8];
  const float* a2s = (const float*)d_in[9];
  const float* a2d = (const float*)d_in[10];
  const float* b2  = (const float*)d_in[11];
  float* out = (float*)d_out;

  char* p = (char*)d_ws;
  auto alloc = [&](size_t bytes) -> void* {
    void* r = (void*)p;
    p += (bytes + 255) & ~(size_t)255;
    return r;
  };
  // ---- contiguous zero region (excludes Vb: no race with V-build blocks) ----
  float* Z     = (float*)alloc((size_t)N_ * ZS_ * 4);      // 3 MB
  float* den1  = (float*)alloc((size_t)N_ * H_ * 4);       // 512 KB
  float* a0    = (float*)alloc((size_t)N_ * H_ * 4);
  float* a1    = (float*)alloc((size_t)N_ * H_ * 4);
  float* ad    = (float*)alloc((size_t)N_ * H_ * 4);
  float* den2  = (float*)alloc((size_t)N_ * 4);            // 64 KB
  float* o0    = (float*)alloc((size_t)N_ * 4);
  float* o1    = (float*)alloc((size_t)N_ * 4);
  // ---- end zero region ----
  unsigned short* Vb = (unsigned short*)alloc((size_t)3 * 32 * 64 * 8 * 2); // 96 KB, pad cols garbage-ok
  float* cb    = (float*)alloc(256);

  size_t zrBytes = (size_t)((char*)Vb - (char*)Z);
  int n16 = (int)(zrBytes / 16);
  int nzb = (n16 + 255) / 256;

  prep<<<dim3(NVB + 1 + nzb), dim3(256), 0, stream>>>(W1s, W1d, a1s, a1d, W2s, W2d,
                                                      a2d, b1, Vb, cb, (uint4*)Z, n16);
  node_mfma<<<dim3(N_ / 16, KSPLIT), dim3(64), 0, stream>>>(x, Vb, Z);
  edge1<<<dim3(ET_ * H_ / 256), dim3(256), 0, stream>>>(ei, Z, den1, a0, a1, ad);
  edge2<<<dim3(ET_ / 256), dim3(256), 0, stream>>>(ei, den1, a0, a1, ad, cb, a2s,
                                                   den2, o0, o1);
  node_out<<<dim3(N_ / 256), dim3(256), 0, stream>>>(den2, o0, o1, b2, out);
}